// Round 7
// baseline (176.031 us; speedup 1.0000x reference)
//
#include <hip/hip_runtime.h>

// S = 1024*1024, ranks [1,3,3,3,3,1].
#define SDIM (1024 * 1024)
#define GROUPS (SDIM / 4)            // float4 groups of s (262144)
#define NBLK 1024                    // K1 blocks: 256 z-groups each (1/thread)
#define NPLANE 10                    // TT0 (1 plane) + TT1..TT3 (3 planes each)

// K1: z-dedup. Evidence (r2/r4 warm replays: FETCH~0 yet same 44us; issue-count
// arithmetic: only 640 wave-loads/CU -> latency model predicts ~5us) says K1 is
// capped by per-CU vector-return byte throughput (~6.2 B/cyc/CU = 3.87 TB/s),
// common to cache hits and HBM. Only lever: demand bytes. Round-0 re-read z
// once per plane (40 MB of the 164 MB demand). Here each thread holds its z
// float4 in registers and contracts it against ALL 10 planes: demand drops to
// 128 MB -> predicted K1 ~34us. 31 loads / 30 accs / 120 FMAs per thread;
// round-0's exact FMA mapping; no LDS in the main loop.
__global__ __launch_bounds__(256) void ftt_k1(
    const float* __restrict__ z,
    const float* __restrict__ t0,
    const float* __restrict__ t1,
    const float* __restrict__ t2,
    const float* __restrict__ t3,
    float* __restrict__ partials)   // [NPLANE][NBLK][4]
{
    const int g = blockIdx.x * 256 + threadIdx.x;    // this thread's float4 group
    const float4 z4 = reinterpret_cast<const float4*>(z)[g];

    const float* bases[NPLANE];
    bases[0] = t0;
    bases[1] = t1;  bases[2] = t1 + 3 * SDIM;  bases[3] = t1 + 6 * SDIM;
    bases[4] = t2;  bases[5] = t2 + 3 * SDIM;  bases[6] = t2 + 6 * SDIM;
    bases[7] = t3;  bases[8] = t3 + 3 * SDIM;  bases[9] = t3 + 6 * SDIM;

    float a0[NPLANE], a1[NPLANE], a2[NPLANE];
    #pragma unroll
    for (int p = 0; p < NPLANE; ++p) {
        const float4* pf = reinterpret_cast<const float4*>(bases[p]) + 3 * g;
        const float4 c0 = pf[0], c1 = pf[1], c2 = pf[2];
        // acc[q] = sum_j z_j * tt[3j+q]; tt flat = c0.xyzw c1.xyzw c2.xyzw
        a0[p] = z4.x * c0.x + z4.y * c0.w + z4.z * c1.z + z4.w * c2.y;
        a1[p] = z4.x * c0.y + z4.y * c1.x + z4.z * c1.w + z4.w * c2.z;
        a2[p] = z4.x * c0.z + z4.y * c1.y + z4.z * c2.x + z4.w * c2.w;
    }

    // wave (64) shuffle reduction of 30 values
    #pragma unroll
    for (int off = 32; off > 0; off >>= 1) {
        #pragma unroll
        for (int p = 0; p < NPLANE; ++p) {
            a0[p] += __shfl_down(a0[p], off, 64);
            a1[p] += __shfl_down(a1[p], off, 64);
            a2[p] += __shfl_down(a2[p], off, 64);
        }
    }

    __shared__ float red[4][NPLANE * 3];
    const int lane = threadIdx.x & 63;
    const int wave = threadIdx.x >> 6;
    if (lane == 0) {
        #pragma unroll
        for (int p = 0; p < NPLANE; ++p) {
            red[wave][p * 3 + 0] = a0[p];
            red[wave][p * 3 + 1] = a1[p];
            red[wave][p * 3 + 2] = a2[p];
        }
    }
    __syncthreads();
    if (threadIdx.x < NPLANE * 3) {
        const int p = threadIdx.x / 3, q = threadIdx.x % 3;
        const float s = red[0][threadIdx.x] + red[1][threadIdx.x]
                      + red[2][threadIdx.x] + red[3][threadIdx.x];
        partials[(p * NBLK + blockIdx.x) * 4 + q] = s;
    }
}

// K2: reduce [NPLANE][NBLK] partial triples -> 30 sums -> f = V0@V1@V2@V3 (3 floats)
__global__ __launch_bounds__(256) void ftt_k2(
    const float* __restrict__ partials,
    float* __restrict__ fvec)
{
    __shared__ float red[NPLANE * 3][8];
    const int job = threadIdx.x >> 3;   // 0..31 (30 used): job = plane*3 + c
    const int sub = threadIdx.x & 7;    // 8 threads per job, NBLK/8 blocks each
    if (job < NPLANE * 3) {
        const int plane = job / 3, c = job % 3;
        float s = 0.0f;
        const int b0 = sub * (NBLK / 8);
        #pragma unroll 4
        for (int b = b0; b < b0 + (NBLK / 8); ++b)
            s += partials[(plane * NBLK + b) * 4 + c];
        red[job][sub] = s;
    }
    __syncthreads();

    if (threadIdx.x == 0) {
        float sum[NPLANE * 3];
        #pragma unroll
        for (int i = 0; i < NPLANE * 3; ++i) {
            float t = 0.0f;
            #pragma unroll
            for (int g = 0; g < 8; ++g) t += red[i][g];
            sum[i] = t;
        }
        float f0 = sum[0], f1 = sum[1], f2 = sum[2];
        #pragma unroll
        for (int k = 0; k < 3; ++k) {
            const float* V = &sum[3 + k * 9];   // V[r*3+q]
            const float n0 = f0 * V[0] + f1 * V[3] + f2 * V[6];
            const float n1 = f0 * V[1] + f1 * V[4] + f2 * V[7];
            const float n2 = f0 * V[2] + f1 * V[5] + f2 * V[8];
            f0 = n0; f1 = n1; f2 = n2;
        }
        fvec[0] = f0; fvec[1] = f1; fvec[2] = f2;
    }
}

// K3: out[s] = f0*TT4[0,s] + f1*TT4[1,s] + f2*TT4[2,s]   (TT4 is (3,S,1))
__global__ __launch_bounds__(256) void ftt_k3(
    const float* __restrict__ t4,
    const float* __restrict__ fvec,
    float* __restrict__ out)
{
    const int i = blockIdx.x * blockDim.x + threadIdx.x;   // float4 index
    const float f0 = fvec[0], f1 = fvec[1], f2 = fvec[2];
    const float4 a = reinterpret_cast<const float4*>(t4)[i];
    const float4 b = reinterpret_cast<const float4*>(t4 + SDIM)[i];
    const float4 c = reinterpret_cast<const float4*>(t4 + 2 * SDIM)[i];
    float4 o;
    o.x = f0 * a.x + f1 * b.x + f2 * c.x;
    o.y = f0 * a.y + f1 * b.y + f2 * c.y;
    o.z = f0 * a.z + f1 * b.z + f2 * c.z;
    o.w = f0 * a.w + f1 * b.w + f2 * c.w;
    reinterpret_cast<float4*>(out)[i] = o;
}

extern "C" void kernel_launch(void* const* d_in, const int* in_sizes, int n_in,
                              void* d_out, int out_size, void* d_ws, size_t ws_size,
                              hipStream_t stream)
{
    const float* z  = (const float*)d_in[0];
    const float* t0 = (const float*)d_in[1];
    const float* t1 = (const float*)d_in[2];
    const float* t2 = (const float*)d_in[3];
    const float* t3 = (const float*)d_in[4];
    const float* t4 = (const float*)d_in[5];
    float* out = (float*)d_out;

    // partials (NPLANE*NBLK*4 floats = 160 KB) live in d_out scratch: K2 consumes
    // them before K3 overwrites the whole buffer (validated in round 1). fvec in ws.
    float* partials = (float*)d_out;
    float* fvec     = (float*)d_ws;

    ftt_k1<<<NBLK, 256, 0, stream>>>(z, t0, t1, t2, t3, partials);
    ftt_k2<<<1, 256, 0, stream>>>(partials, fvec);
    ftt_k3<<<SDIM / 4 / 256, 256, 0, stream>>>(t4, fvec, out);
}

// Round 8
// 169.106 us; speedup vs baseline: 1.0409x; 1.0409x over previous
//
#include <hip/hip_runtime.h>

// S = 1024*1024, ranks [1,3,3,3,3,1].
#define SDIM (1024 * 1024)
#define GROUPS (SDIM / 4)            // float4 groups of s (262144)
#define GPT 4                        // float4-groups per thread in K1
#define CHUNKS (GROUPS / (256 * GPT))// 256 chunks per plane
#define NPLANE 10                    // TT0 (1 plane) + TT1..TT3 (3 planes each)

// K1: EXACT round-0 structure (best measured: 42.4-44.6 us across 7 rounds;
// invariant to pattern/bytes/occupancy/MLP — streaming ~120 MB of once-used
// plane data sits at the chip's ~2.8 TB/s fill-path floor). Single change:
// the tail atomicAdds each block's 3 plane-sums directly into a 30-float
// global accumulator (d_ws, zeroed by a captured hipMemsetAsync), eliminating
// the K2 kernel + its launch bubble. 3 atomics/block, 256 per address: no
// contention; float reorder noise ~1e-7 rel, tolerance 1.15e-3.
__global__ __launch_bounds__(256) void ftt_k1(
    const float* __restrict__ z,
    const float* __restrict__ t0,
    const float* __restrict__ t1,
    const float* __restrict__ t2,
    const float* __restrict__ t3,
    float* __restrict__ sums)       // [NPLANE*3] atomic accumulators
{
    const int plane = blockIdx.y;

    const float* base;
    if (plane == 0) {
        base = t0;
    } else {
        const int pk = plane - 1;
        const int k = pk / 3;                        // wave-uniform
        const float* tk = (k == 0) ? t1 : (k == 1) ? t2 : t3;
        base = tk + (pk % 3) * (3 * SDIM);
    }

    const int g0 = blockIdx.x * (256 * GPT) + threadIdx.x;
    float a0 = 0.0f, a1 = 0.0f, a2 = 0.0f;

    #pragma unroll
    for (int it = 0; it < GPT; ++it) {
        const int g = g0 + it * 256;
        const float4 z4 = reinterpret_cast<const float4*>(z)[g];
        const float4* p = reinterpret_cast<const float4*>(base + 12 * g);
        const float4 c0 = p[0], c1 = p[1], c2 = p[2];
        // acc[q] += sum_j z_j * tt[3j+q]; tt flat = c0.xyzw c1.xyzw c2.xyzw
        a0 += z4.x * c0.x + z4.y * c0.w + z4.z * c1.z + z4.w * c2.y;
        a1 += z4.x * c0.y + z4.y * c1.x + z4.z * c1.w + z4.w * c2.z;
        a2 += z4.x * c0.z + z4.y * c1.y + z4.z * c2.x + z4.w * c2.w;
    }

    // wave (64) shuffle reduction
    #pragma unroll
    for (int off = 32; off > 0; off >>= 1) {
        a0 += __shfl_down(a0, off, 64);
        a1 += __shfl_down(a1, off, 64);
        a2 += __shfl_down(a2, off, 64);
    }

    __shared__ float red[4][3];
    const int lane = threadIdx.x & 63;
    const int wave = threadIdx.x >> 6;
    if (lane == 0) { red[wave][0] = a0; red[wave][1] = a1; red[wave][2] = a2; }
    __syncthreads();
    if (threadIdx.x < 3) {
        const int c = threadIdx.x;
        const float s = red[0][c] + red[1][c] + red[2][c] + red[3][c];
        atomicAdd(&sums[plane * 3 + c], s);
    }
}

// K3: every block redundantly computes the 3-float chain product
//   f = V0 @ V1 @ V2 @ V3 from the 30 sums (36 flops, L2-broadcast read),
// then out[s] = f0*TT4[0,s] + f1*TT4[1,s] + f2*TT4[2,s]   (TT4 is (3,S,1)).
__global__ __launch_bounds__(256) void ftt_k3(
    const float* __restrict__ t4,
    const float* __restrict__ sums,
    float* __restrict__ out)
{
    // chain product (wave-uniform; sums[plane*3+q], plane = 1+3k+r)
    float f0 = sums[0], f1 = sums[1], f2 = sums[2];
    #pragma unroll
    for (int k = 0; k < 3; ++k) {
        const int b = 3 + 9 * k;                 // == (1+3k)*3
        const float n0 = f0 * sums[b + 0] + f1 * sums[b + 3] + f2 * sums[b + 6];
        const float n1 = f0 * sums[b + 1] + f1 * sums[b + 4] + f2 * sums[b + 7];
        const float n2 = f0 * sums[b + 2] + f1 * sums[b + 5] + f2 * sums[b + 8];
        f0 = n0; f1 = n1; f2 = n2;
    }

    const int i = blockIdx.x * blockDim.x + threadIdx.x;   // float4 index
    const float4 a = reinterpret_cast<const float4*>(t4)[i];
    const float4 b = reinterpret_cast<const float4*>(t4 + SDIM)[i];
    const float4 c = reinterpret_cast<const float4*>(t4 + 2 * SDIM)[i];
    float4 o;
    o.x = f0 * a.x + f1 * b.x + f2 * c.x;
    o.y = f0 * a.y + f1 * b.y + f2 * c.y;
    o.z = f0 * a.z + f1 * b.z + f2 * c.z;
    o.w = f0 * a.w + f1 * b.w + f2 * c.w;
    reinterpret_cast<float4*>(out)[i] = o;
}

extern "C" void kernel_launch(void* const* d_in, const int* in_sizes, int n_in,
                              void* d_out, int out_size, void* d_ws, size_t ws_size,
                              hipStream_t stream)
{
    const float* z  = (const float*)d_in[0];
    const float* t0 = (const float*)d_in[1];
    const float* t1 = (const float*)d_in[2];
    const float* t2 = (const float*)d_in[3];
    const float* t3 = (const float*)d_in[4];
    const float* t4 = (const float*)d_in[5];
    float* out = (float*)d_out;

    float* sums = (float*)d_ws;                  // 30 floats, zeroed per launch

    // async memset is graph-capturable (becomes a memset node); required
    // because the harness replays this launch sequence many times.
    hipMemsetAsync(sums, 0, NPLANE * 3 * sizeof(float), stream);
    ftt_k1<<<dim3(CHUNKS, NPLANE), 256, 0, stream>>>(z, t0, t1, t2, t3, sums);
    ftt_k3<<<SDIM / 4 / 256, 256, 0, stream>>>(t4, sums, out);
}

// Round 9
// 168.505 us; speedup vs baseline: 1.0447x; 1.0036x over previous
//
#include <hip/hip_runtime.h>

// S = 1024*1024, ranks [1,3,3,3,3,1].
// FINAL (reverted to best-measured R0/R3 structure, 166.96 us).
// Session findings: K1 streams 124 MB of once-used plane data at the chip's
// ~2.9 TB/s L3/fabric fill-path rate — invariant to access pattern, demand
// bytes, cache residency, occupancy, forced MLP, and kernel fusion (rounds
// 1-8). Non-K1 time (~124 us) is the harness's fixed dispatch train. No
// source-level lever remains: read-once data, zero reuse.
#define SDIM (1024 * 1024)
#define GROUPS (SDIM / 4)            // float4 groups of s (262144)
#define GPT 4                        // float4-groups per thread in K1
#define CHUNKS (GROUPS / (256 * GPT))// 256 chunks per plane
#define NPLANE 10                    // TT0 (1 plane) + TT1..TT3 (3 planes each)

// K1: grid (CHUNKS, NPLANE). Each block computes a partial 3-vector:
//   part[plane][chunk][q] = sum_{s in chunk} z[s] * plane[s*3 + q]
__global__ __launch_bounds__(256) void ftt_k1(
    const float* __restrict__ z,
    const float* __restrict__ t0,
    const float* __restrict__ t1,
    const float* __restrict__ t2,
    const float* __restrict__ t3,
    float* __restrict__ partials)   // [NPLANE][CHUNKS][4]
{
    const int plane = blockIdx.y;

    const float* base;
    if (plane == 0) {
        base = t0;
    } else {
        const int pk = plane - 1;
        const int k = pk / 3;                        // wave-uniform
        const float* tk = (k == 0) ? t1 : (k == 1) ? t2 : t3;
        base = tk + (pk % 3) * (3 * SDIM);
    }

    const int g0 = blockIdx.x * (256 * GPT) + threadIdx.x;
    float a0 = 0.0f, a1 = 0.0f, a2 = 0.0f;

    #pragma unroll
    for (int it = 0; it < GPT; ++it) {
        const int g = g0 + it * 256;
        const float4 z4 = reinterpret_cast<const float4*>(z)[g];
        const float4* p = reinterpret_cast<const float4*>(base + 12 * g);
        const float4 c0 = p[0], c1 = p[1], c2 = p[2];
        // acc[q] += sum_j z_j * tt[3j+q]; tt flat = c0.xyzw c1.xyzw c2.xyzw
        a0 += z4.x * c0.x + z4.y * c0.w + z4.z * c1.z + z4.w * c2.y;
        a1 += z4.x * c0.y + z4.y * c1.x + z4.z * c1.w + z4.w * c2.z;
        a2 += z4.x * c0.z + z4.y * c1.y + z4.z * c2.x + z4.w * c2.w;
    }

    // wave (64) shuffle reduction
    #pragma unroll
    for (int off = 32; off > 0; off >>= 1) {
        a0 += __shfl_down(a0, off, 64);
        a1 += __shfl_down(a1, off, 64);
        a2 += __shfl_down(a2, off, 64);
    }

    __shared__ float red[4][3];
    const int lane = threadIdx.x & 63;
    const int wave = threadIdx.x >> 6;
    if (lane == 0) { red[wave][0] = a0; red[wave][1] = a1; red[wave][2] = a2; }
    __syncthreads();
    if (threadIdx.x < 3) {
        const int c = threadIdx.x;
        const float s = red[0][c] + red[1][c] + red[2][c] + red[3][c];
        partials[(plane * CHUNKS + blockIdx.x) * 4 + c] = s;
    }
}

// K2: reduce [NPLANE][CHUNKS] partial triples -> 30 sums -> f = V0@V1@V2@V3 (3 floats)
__global__ __launch_bounds__(256) void ftt_k2(
    const float* __restrict__ partials,
    float* __restrict__ fvec)
{
    __shared__ float red[NPLANE * 3][8];
    const int job = threadIdx.x >> 3;   // 0..31 (30 used): job = plane*3 + c
    const int sub = threadIdx.x & 7;    // 8 threads per job, CHUNKS/8 chunks each
    if (job < NPLANE * 3) {
        const int plane = job / 3, c = job % 3;
        float s = 0.0f;
        const int b0 = sub * (CHUNKS / 8);
        #pragma unroll 4
        for (int b = b0; b < b0 + (CHUNKS / 8); ++b)
            s += partials[(plane * CHUNKS + b) * 4 + c];
        red[job][sub] = s;
    }
    __syncthreads();

    if (threadIdx.x == 0) {
        float sum[NPLANE * 3];
        #pragma unroll
        for (int i = 0; i < NPLANE * 3; ++i) {
            float t = 0.0f;
            #pragma unroll
            for (int g = 0; g < 8; ++g) t += red[i][g];
            sum[i] = t;
        }
        float f0 = sum[0], f1 = sum[1], f2 = sum[2];
        #pragma unroll
        for (int k = 0; k < 3; ++k) {
            const float* V = &sum[3 + k * 9];   // V[r*3+q]
            const float n0 = f0 * V[0] + f1 * V[3] + f2 * V[6];
            const float n1 = f0 * V[1] + f1 * V[4] + f2 * V[7];
            const float n2 = f0 * V[2] + f1 * V[5] + f2 * V[8];
            f0 = n0; f1 = n1; f2 = n2;
        }
        fvec[0] = f0; fvec[1] = f1; fvec[2] = f2;
    }
}

// K3: out[s] = f0*TT4[0,s] + f1*TT4[1,s] + f2*TT4[2,s]   (TT4 is (3,S,1))
__global__ __launch_bounds__(256) void ftt_k3(
    const float* __restrict__ t4,
    const float* __restrict__ fvec,
    float* __restrict__ out)
{
    const int i = blockIdx.x * blockDim.x + threadIdx.x;   // float4 index
    const float f0 = fvec[0], f1 = fvec[1], f2 = fvec[2];
    const float4 a = reinterpret_cast<const float4*>(t4)[i];
    const float4 b = reinterpret_cast<const float4*>(t4 + SDIM)[i];
    const float4 c = reinterpret_cast<const float4*>(t4 + 2 * SDIM)[i];
    float4 o;
    o.x = f0 * a.x + f1 * b.x + f2 * c.x;
    o.y = f0 * a.y + f1 * b.y + f2 * c.y;
    o.z = f0 * a.z + f1 * b.z + f2 * c.z;
    o.w = f0 * a.w + f1 * b.w + f2 * c.w;
    reinterpret_cast<float4*>(out)[i] = o;
}

extern "C" void kernel_launch(void* const* d_in, const int* in_sizes, int n_in,
                              void* d_out, int out_size, void* d_ws, size_t ws_size,
                              hipStream_t stream)
{
    const float* z  = (const float*)d_in[0];
    const float* t0 = (const float*)d_in[1];
    const float* t1 = (const float*)d_in[2];
    const float* t2 = (const float*)d_in[3];
    const float* t3 = (const float*)d_in[4];
    const float* t4 = (const float*)d_in[5];
    float* out = (float*)d_out;

    float* partials = (float*)d_ws;                      // NPLANE*CHUNKS*4 floats
    float* fvec     = partials + NPLANE * CHUNKS * 4;    // 3 floats

    ftt_k1<<<dim3(CHUNKS, NPLANE), 256, 0, stream>>>(z, t0, t1, t2, t3, partials);
    ftt_k2<<<1, 256, 0, stream>>>(partials, fvec);
    ftt_k3<<<SDIM / 4 / 256, 256, 0, stream>>>(t4, fvec, out);
}